// Round 2
// baseline (368.013 us; speedup 1.0000x reference)
//
#include <hip/hip_runtime.h>
#include <hip/hip_bf16.h>

typedef __attribute__((ext_vector_type(8))) short short8;   // 8 bf16 = 4 VGPRs (MFMA A/B frag)
typedef __attribute__((ext_vector_type(4))) short short4v;  // 4 bf16 = 8 B
typedef __attribute__((ext_vector_type(4))) float floatx4;  // MFMA C/D frag

#define MFMA(a, b, c) __builtin_amdgcn_mfma_f32_16x16x32_bf16((a), (b), (c), 0, 0, 0)

// fp32 -> bf16, round-to-nearest-even (bit trick; inputs are finite)
__device__ __forceinline__ short f2bf(float f) {
    unsigned u = __float_as_uint(f);
    u += 0x7fffu + ((u >> 16) & 1u);
    return (short)(u >> 16);
}

__device__ __forceinline__ short8 pack_bf16(floatx4 a, floatx4 b) {
    short8 r;
    r[0] = f2bf(a.x); r[1] = f2bf(a.y); r[2] = f2bf(a.z); r[3] = f2bf(a.w);
    r[4] = f2bf(b.x); r[5] = f2bf(b.y); r[6] = f2bf(b.z); r[7] = f2bf(b.w);
    return r;
}

// ---------------------------------------------------------------------------
// Cayley via Neumann/Horner series on one block (256 threads, 4 waves).
//   B = skew(X)/2 (||B||_2 ~ 0.16);  C = I + 2*(B + B^2 + ...)
// NSTEP=6 -> truncation ~4e-5, far below bf16 rounding.
// mode 0: write C row-major bf16 (B-operand array)
// mode 1: write C^T * diag bf16  (A-operand array, diag folded)
// ---------------------------------------------------------------------------
__device__ void cayley64(const float* __restrict__ X, const float* __restrict__ dg,
                         short* outArr, int mode,
                         short* Brow, float* Bcol, short* T0, short* T1, int tid)
{
    int i0 = (tid * 16) >> 6;
    int j0 = (tid * 16) & 63;
#pragma unroll
    for (int s = 0; s < 16; ++s) {
        int i = i0, j = j0 + s;
        float b = 0.f;
        if (i > j)      b =  0.5f * X[i * 64 + j];
        else if (i < j) b = -0.5f * X[j * 64 + i];
        Brow[i * 72 + j] = f2bf(b);
        Bcol[j * 68 + i] = b;
        T0[j * 72 + i]   = f2bf(b);
    }
    __syncthreads();

    int lane = tid & 63, w = tid >> 6, m = lane & 15, q = lane >> 4;
    int arow = (w * 16 + m) * 72;
    short8 a0 = *(const short8*)&Brow[arow + q * 8];
    short8 a1 = *(const short8*)&Brow[arow + 32 + q * 8];

    short* Tbuf[2] = {T0, T1};
    int cur = 0;
    const int NSTEP = 6;
    for (int step = 0; step < NSTEP; ++step) {
        bool last = (step == NSTEP - 1);
        short* Tr = Tbuf[cur];
        short* Tw = Tbuf[cur ^ 1];
#pragma unroll
        for (int c = 0; c < 4; ++c) {
            int coff = c * 16 + m;
            short8 b0 = *(const short8*)&Tr[coff * 72 + q * 8];
            short8 b1 = *(const short8*)&Tr[coff * 72 + 32 + q * 8];
            floatx4 acc = {0.f, 0.f, 0.f, 0.f};
            acc = MFMA(a0, b0, acc);
            acc = MFMA(a1, b1, acc);
            int row0 = w * 16 + q * 4;
            floatx4 badd = *(const floatx4*)&Bcol[coff * 68 + row0];
            floatx4 t = badd + acc;                 // T_new = B + B*T_old
            if (!last) {
                short4v pk = { f2bf(t.x), f2bf(t.y), f2bf(t.z), f2bf(t.w) };
                *(short4v*)&Tw[coff * 72 + row0] = pk;
            } else {
                int col = coff;
                floatx4 cv;
                cv.x = ((row0 + 0) == col ? 1.f : 0.f) + 2.f * t.x;
                cv.y = ((row0 + 1) == col ? 1.f : 0.f) + 2.f * t.y;
                cv.z = ((row0 + 2) == col ? 1.f : 0.f) + 2.f * t.z;
                cv.w = ((row0 + 3) == col ? 1.f : 0.f) + 2.f * t.w;
                if (mode == 0) {
                    outArr[(row0 + 0) * 72 + col] = f2bf(cv.x);
                    outArr[(row0 + 1) * 72 + col] = f2bf(cv.y);
                    outArr[(row0 + 2) * 72 + col] = f2bf(cv.z);
                    outArr[(row0 + 3) * 72 + col] = f2bf(cv.w);
                } else {
                    floatx4 dv = *(const floatx4*)&dg[row0];
                    short4v pk = { f2bf(cv.x * dv.x), f2bf(cv.y * dv.y),
                                   f2bf(cv.z * dv.z), f2bf(cv.w * dv.w) };
                    *(short4v*)&outArr[col * 72 + row0] = pk;
                }
            }
        }
        __syncthreads();
        cur ^= 1;
    }
}

// ---------------------------------------------------------------------------
// k_prep: 2 blocks. Block 0 -> m_left^T, block 1 -> m_right^T (bf16 row-major)
// ---------------------------------------------------------------------------
__global__ __launch_bounds__(256) void k_prep(
        const float* __restrict__ u_l, const float* __restrict__ v_l, const float* __restrict__ dg_l,
        const float* __restrict__ u_r, const float* __restrict__ v_r, const float* __restrict__ dg_r,
        short* __restrict__ wsOut)
{
    __shared__ __align__(16) short Brow[64 * 72];
    __shared__ __align__(16) float Bcol[64 * 68];
    __shared__ __align__(16) short T0[64 * 72];
    __shared__ __align__(16) short T1[64 * 72];
    __shared__ __align__(16) short CvA[64 * 72];
    __shared__ __align__(16) short CuB[64 * 72];

    int tid = threadIdx.x;
    const float* U  = (blockIdx.x == 0) ? u_l  : u_r;
    const float* V  = (blockIdx.x == 0) ? v_l  : v_r;
    const float* DG = (blockIdx.x == 0) ? dg_l : dg_r;
    short* outT = wsOut + blockIdx.x * 4096;

    cayley64(V, DG, CvA, 1, Brow, Bcol, T0, T1, tid);
    __syncthreads();
    cayley64(U, DG, CuB, 0, Brow, Bcol, T0, T1, tid);
    __syncthreads();

    int lane = tid & 63, w = tid >> 6, m = lane & 15, q = lane >> 4;
    int arow = (w * 16 + m) * 72;
    short8 a0 = *(const short8*)&CvA[arow + q * 8];
    short8 a1 = *(const short8*)&CvA[arow + 32 + q * 8];
#pragma unroll
    for (int c = 0; c < 4; ++c) {
        short8 b0 = *(const short8*)&CuB[(c * 16 + m) * 72 + q * 8];
        short8 b1 = *(const short8*)&CuB[(c * 16 + m) * 72 + 32 + q * 8];
        floatx4 acc = {0.f, 0.f, 0.f, 0.f};
        acc = MFMA(a0, b0, acc);
        acc = MFMA(a1, b1, acc);
        int row0 = w * 16 + q * 4, col = c * 16 + m;
        outT[(row0 + 0) * 64 + col] = f2bf(acc.x);
        outT[(row0 + 1) * 64 + col] = f2bf(acc.y);
        outT[(row0 + 2) * 64 + col] = f2bf(acc.z);
        outT[(row0 + 3) * 64 + col] = f2bf(acc.w);
    }
}

// ---------------------------------------------------------------------------
// k_main v5: out_n = P @ (x_n * dscale) @ Q, barrier-free, wave-private LDS.
// Changes vs v4 (which was latency-exposed: 1KB prefetch depth, stall ~90%):
//  1. FULL-MATRIX prefetch (16 dwordx4 = 4KB/wave in flight), issued a whole
//     matrix-compute ahead. Queue order [L(i)][S(i-1)][L(i+1)] -> the wait
//     for L(i) is vmcnt(32): never drains stores (max 48 outstanding < 63).
//  2. dscale pinned in 64 VGPRs (identical for every matrix) -> the ONLY
//     in-loop VMEM ops are 16 x-loads + 16 out-stores per matrix.
//  3. Phase B computes O^T = S^T @ P^T by SWAPPING MFMA operands:
//     existing LDS S^T reads are the A-frag, existing P-row frags are
//     exactly the B-frag of P^T (layout-identical). D then holds 4
//     consecutive output columns per lane -> 16 dwordx4 stores (plain, not
//     nt: v4's nt half-line stores amplified WRITE_SIZE 131->161 MB).
//     Bit-identical products & accumulation order vs v4.
//  LDS 4x9216B = 36864 -> 4 blocks/CU = 16 waves/CU (binding limit);
//  VGPR ~250-300 is free at 4 waves/SIMD (4x300 < 2048).
// ---------------------------------------------------------------------------
#define MPW 2   // matrices per wave; grid = N / (4 waves * MPW) = 1024 blocks

__device__ __forceinline__ void compute_mat(
        const floatx4* xr, const floatx4* dsr,
        const short8 (*qf)[2], const short8 (*pf)[2],
        short* st, float* op, int m, int q)
{
    // ---- phase A: S = Xs @ Q, write S^T slices to private LDS
#pragma unroll
    for (int rt = 0; rt < 4; ++rt) {
        short8 a0 = pack_bf16(xr[rt * 4 + 0] * dsr[rt * 4 + 0],
                              xr[rt * 4 + 1] * dsr[rt * 4 + 1]);   // k = 0..31
        short8 a1 = pack_bf16(xr[rt * 4 + 2] * dsr[rt * 4 + 2],
                              xr[rt * 4 + 3] * dsr[rt * 4 + 3]);   // k = 32..63
#pragma unroll
        for (int c = 0; c < 4; ++c) {
            floatx4 s = {0.f, 0.f, 0.f, 0.f};
            s = MFMA(a0, qf[c][0], s);
            s = MFMA(a1, qf[c][1], s);
            short4v pk = { f2bf(s.x), f2bf(s.y), f2bf(s.z), f2bf(s.w) };
            *(short4v*)&st[(c * 16 + m) * 72 + rt * 16 + q * 4] = pk;
        }
    }
    // ---- phase B: O^T = S^T @ P^T (operand-swapped) -> dwordx4 row stores
#pragma unroll
    for (int c2 = 0; c2 < 4; ++c2) {
        short8 sb0 = *(const short8*)&st[(c2 * 16 + m) * 72 + q * 8];
        short8 sb1 = *(const short8*)&st[(c2 * 16 + m) * 72 + 32 + q * 8];
#pragma unroll
        for (int r = 0; r < 4; ++r) {
            floatx4 o = {0.f, 0.f, 0.f, 0.f};
            o = MFMA(sb0, pf[r][0], o);   // A = S^T rows, B = P^T cols
            o = MFMA(sb1, pf[r][1], o);
            // lane holds O[r*16+m][c2*16+q*4 .. +3] -> contiguous 16B
            *(floatx4*)&op[(r * 16 + m) * 64 + c2 * 16 + q * 4] = o;
        }
    }
}

__global__ __launch_bounds__(256, 4) void k_main(
        const float* __restrict__ x, const float* __restrict__ dsc,
        const short* __restrict__ mLT, const short* __restrict__ mRT,
        float* __restrict__ out, int N)
{
    __shared__ __align__(16) short ST[4][64 * 72];   // per-wave private S^T

    const int tid = threadIdx.x;
    const int w = tid >> 6, lane = tid & 63, m = lane & 15, q = lane >> 4;
    short* st = ST[w];

    // P-row frags (serve as B-operand of P^T in phase B) and Q^T frags
    short8 pf[4][2], qf[4][2];
#pragma unroll
    for (int r = 0; r < 4; ++r) {
        pf[r][0] = *(const short8*)&mLT[(r * 16 + m) * 64 + q * 8];
        pf[r][1] = *(const short8*)&mLT[(r * 16 + m) * 64 + 32 + q * 8];
        qf[r][0] = *(const short8*)&mRT[(r * 16 + m) * 64 + q * 8];
        qf[r][1] = *(const short8*)&mRT[(r * 16 + m) * 64 + 32 + q * 8];
    }

    const int loff = m * 64 + q * 8;       // lane's float offset within a chunk
    constexpr int co[4] = {0, 4, 32, 36};  // intra-chunk dword offsets

    // dscale resident in registers: identical for every matrix (64 VGPRs)
    floatx4 dsr[16];
#pragma unroll
    for (int rt = 0; rt < 4; ++rt) {
        const float* dp = dsc + rt * 1024 + loff;
#pragma unroll
        for (int c = 0; c < 4; ++c)
            dsr[rt * 4 + c] = *(const floatx4*)&dp[co[c]];
    }

    const int gw = blockIdx.x * 4 + w;
    const long n0 = (long)gw * MPW;
    if (n0 >= N) return;
    const float* xw = x + (size_t)n0 * 4096 + loff;
    float* ow = out + (size_t)n0 * 4096;

    // ---- prologue: load matrix 0 (16 dwordx4, 4KB in flight)
    floatx4 xa[16], xb[16];
#pragma unroll
    for (int c = 0; c < 16; ++c)
        xa[c] = *(const floatx4*)&xw[(c >> 2) * 1024 + co[c & 3]];

    const bool has2 = (n0 + 1 < N);
    if (has2) {
        // ---- issue ALL matrix-1 loads before any use of matrix-0 regs:
        // the vmcnt wait for xa is then vmcnt(16+), never exposing latency
#pragma unroll
        for (int c = 0; c < 16; ++c)
            xb[c] = *(const floatx4*)&xw[4096 + (c >> 2) * 1024 + co[c & 3]];
    }

    compute_mat(xa, dsr, qf, pf, st, ow, m, q);
    // LDS WAR hazard (m1 phase-A writes over m0 phase-B read addrs) is safe:
    // DS ops from one wave execute in order (v4 relied on the same property).
    if (has2)
        compute_mat(xb, dsr, qf, pf, st, ow + 4096, m, q);
}

extern "C" void kernel_launch(void* const* d_in, const int* in_sizes, int n_in,
                              void* d_out, int out_size, void* d_ws, size_t ws_size,
                              hipStream_t stream) {
    const float* x    = (const float*)d_in[0];
    const float* u_l  = (const float*)d_in[1];
    const float* v_l  = (const float*)d_in[2];
    const float* dg_l = (const float*)d_in[3];
    const float* u_r  = (const float*)d_in[4];
    const float* v_r  = (const float*)d_in[5];
    const float* dg_r = (const float*)d_in[6];
    const float* dsc  = (const float*)d_in[7];
    float* out = (float*)d_out;
    short* ws  = (short*)d_ws;   // [0..4095]=m_left^T bf16, [4096..8191]=m_right^T bf16

    int N = in_sizes[0] / 4096;  // 8192 matrices of 64x64

    hipLaunchKernelGGL(k_prep, dim3(2), dim3(256), 0, stream,
                       u_l, v_l, dg_l, u_r, v_r, dg_r, ws);
    int grid = (N + MPW * 4 - 1) / (MPW * 4);
    hipLaunchKernelGGL(k_main, dim3(grid), dim3(256), 0, stream,
                       x, dsc, ws, ws + 4096, out, N);
}

// Round 3
// 270.546 us; speedup vs baseline: 1.3603x; 1.3603x over previous
//
#include <hip/hip_runtime.h>
#include <hip/hip_bf16.h>

typedef __attribute__((ext_vector_type(8))) short short8;   // 8 bf16 = 4 VGPRs (MFMA A/B frag)
typedef __attribute__((ext_vector_type(4))) short short4v;  // 4 bf16 = 8 B
typedef __attribute__((ext_vector_type(4))) float floatx4;  // MFMA C/D frag

#define MFMA(a, b, c) __builtin_amdgcn_mfma_f32_16x16x32_bf16((a), (b), (c), 0, 0, 0)
#define AS1 __attribute__((address_space(1)))
#define AS3 __attribute__((address_space(3)))

// fp32 -> bf16, round-to-nearest-even (bit trick; inputs are finite)
__device__ __forceinline__ short f2bf(float f) {
    unsigned u = __float_as_uint(f);
    u += 0x7fffu + ((u >> 16) & 1u);
    return (short)(u >> 16);
}

__device__ __forceinline__ short8 pack_bf16(floatx4 a, floatx4 b) {
    short8 r;
    r[0] = f2bf(a.x); r[1] = f2bf(a.y); r[2] = f2bf(a.z); r[3] = f2bf(a.w);
    r[4] = f2bf(b.x); r[5] = f2bf(b.y); r[6] = f2bf(b.z); r[7] = f2bf(b.w);
    return r;
}

// ---------------------------------------------------------------------------
// Cayley via Neumann/Horner series on one block (256 threads, 4 waves).
// (unchanged from prior rounds — negligible runtime)
// ---------------------------------------------------------------------------
__device__ void cayley64(const float* __restrict__ X, const float* __restrict__ dg,
                         short* outArr, int mode,
                         short* Brow, float* Bcol, short* T0, short* T1, int tid)
{
    int i0 = (tid * 16) >> 6;
    int j0 = (tid * 16) & 63;
#pragma unroll
    for (int s = 0; s < 16; ++s) {
        int i = i0, j = j0 + s;
        float b = 0.f;
        if (i > j)      b =  0.5f * X[i * 64 + j];
        else if (i < j) b = -0.5f * X[j * 64 + i];
        Brow[i * 72 + j] = f2bf(b);
        Bcol[j * 68 + i] = b;
        T0[j * 72 + i]   = f2bf(b);
    }
    __syncthreads();

    int lane = tid & 63, w = tid >> 6, m = lane & 15, q = lane >> 4;
    int arow = (w * 16 + m) * 72;
    short8 a0 = *(const short8*)&Brow[arow + q * 8];
    short8 a1 = *(const short8*)&Brow[arow + 32 + q * 8];

    short* Tbuf[2] = {T0, T1};
    int cur = 0;
    const int NSTEP = 6;
    for (int step = 0; step < NSTEP; ++step) {
        bool last = (step == NSTEP - 1);
        short* Tr = Tbuf[cur];
        short* Tw = Tbuf[cur ^ 1];
#pragma unroll
        for (int c = 0; c < 4; ++c) {
            int coff = c * 16 + m;
            short8 b0 = *(const short8*)&Tr[coff * 72 + q * 8];
            short8 b1 = *(const short8*)&Tr[coff * 72 + 32 + q * 8];
            floatx4 acc = {0.f, 0.f, 0.f, 0.f};
            acc = MFMA(a0, b0, acc);
            acc = MFMA(a1, b1, acc);
            int row0 = w * 16 + q * 4;
            floatx4 badd = *(const floatx4*)&Bcol[coff * 68 + row0];
            floatx4 t = badd + acc;                 // T_new = B + B*T_old
            if (!last) {
                short4v pk = { f2bf(t.x), f2bf(t.y), f2bf(t.z), f2bf(t.w) };
                *(short4v*)&Tw[coff * 72 + row0] = pk;
            } else {
                int col = coff;
                floatx4 cv;
                cv.x = ((row0 + 0) == col ? 1.f : 0.f) + 2.f * t.x;
                cv.y = ((row0 + 1) == col ? 1.f : 0.f) + 2.f * t.y;
                cv.z = ((row0 + 2) == col ? 1.f : 0.f) + 2.f * t.z;
                cv.w = ((row0 + 3) == col ? 1.f : 0.f) + 2.f * t.w;
                if (mode == 0) {
                    outArr[(row0 + 0) * 72 + col] = f2bf(cv.x);
                    outArr[(row0 + 1) * 72 + col] = f2bf(cv.y);
                    outArr[(row0 + 2) * 72 + col] = f2bf(cv.z);
                    outArr[(row0 + 3) * 72 + col] = f2bf(cv.w);
                } else {
                    floatx4 dv = *(const floatx4*)&dg[row0];
                    short4v pk = { f2bf(cv.x * dv.x), f2bf(cv.y * dv.y),
                                   f2bf(cv.z * dv.z), f2bf(cv.w * dv.w) };
                    *(short4v*)&outArr[col * 72 + row0] = pk;
                }
            }
        }
        __syncthreads();
        cur ^= 1;
    }
}

// ---------------------------------------------------------------------------
// k_prep: 2 blocks. Block 0 -> m_left^T, block 1 -> m_right^T (bf16 row-major)
// ---------------------------------------------------------------------------
__global__ __launch_bounds__(256) void k_prep(
        const float* __restrict__ u_l, const float* __restrict__ v_l, const float* __restrict__ dg_l,
        const float* __restrict__ u_r, const float* __restrict__ v_r, const float* __restrict__ dg_r,
        short* __restrict__ wsOut)
{
    __shared__ __align__(16) short Brow[64 * 72];
    __shared__ __align__(16) float Bcol[64 * 68];
    __shared__ __align__(16) short T0[64 * 72];
    __shared__ __align__(16) short T1[64 * 72];
    __shared__ __align__(16) short CvA[64 * 72];
    __shared__ __align__(16) short CuB[64 * 72];

    int tid = threadIdx.x;
    const float* U  = (blockIdx.x == 0) ? u_l  : u_r;
    const float* V  = (blockIdx.x == 0) ? v_l  : v_r;
    const float* DG = (blockIdx.x == 0) ? dg_l : dg_r;
    short* outT = wsOut + blockIdx.x * 4096;

    cayley64(V, DG, CvA, 1, Brow, Bcol, T0, T1, tid);
    __syncthreads();
    cayley64(U, DG, CuB, 0, Brow, Bcol, T0, T1, tid);
    __syncthreads();

    int lane = tid & 63, w = tid >> 6, m = lane & 15, q = lane >> 4;
    int arow = (w * 16 + m) * 72;
    short8 a0 = *(const short8*)&CvA[arow + q * 8];
    short8 a1 = *(const short8*)&CvA[arow + 32 + q * 8];
#pragma unroll
    for (int c = 0; c < 4; ++c) {
        short8 b0 = *(const short8*)&CuB[(c * 16 + m) * 72 + q * 8];
        short8 b1 = *(const short8*)&CuB[(c * 16 + m) * 72 + 32 + q * 8];
        floatx4 acc = {0.f, 0.f, 0.f, 0.f};
        acc = MFMA(a0, b0, acc);
        acc = MFMA(a1, b1, acc);
        int row0 = w * 16 + q * 4, col = c * 16 + m;
        outT[(row0 + 0) * 64 + col] = f2bf(acc.x);
        outT[(row0 + 1) * 64 + col] = f2bf(acc.y);
        outT[(row0 + 2) * 64 + col] = f2bf(acc.z);
        outT[(row0 + 3) * 64 + col] = f2bf(acc.w);
    }
}

// ---------------------------------------------------------------------------
// k_main v6: out_n = P @ (x_n * dscale) @ Q
//   1 WAVE PER BLOCK (64 thr), barrier-free; wave owns MPW=8 matrices.
//   x staged via global_load_lds DMA (16 x 1KB per matrix), double-buffered,
//   issued ONE MATRIX AHEAD; wave parks on COUNTED s_waitcnt vmcnt(N)
//   (stores + next DMA stay in flight; never vmcnt(0) mid-loop).
//   Per-CU: 4 blocks (LDS 40KB each) x 16KB DMA in flight ~= 64KB outstanding
//   >> BW*latency (~9KB)  => HBM-saturating by Little's law.
//   LDS XOR-swizzle (16B granularity) applied to the DMA *global source*
//   address (dest must stay linear) and matching ds_read side; S^T buffer
//   swizzled the same way (no padding).  dscale pinned in 64 VGPRs.
//   v5's scratch-spill bug avoided: single function body, no arrays passed
//   by pointer, all register arrays indexed by unroll constants.
// ---------------------------------------------------------------------------
#define MPW 8   // matrices per wave; grid = 8192/8 = 1024 = 256 CU x 4 blocks

__global__ __launch_bounds__(64) void k_main(
        const float* __restrict__ x, const float* __restrict__ dsc,
        const short* __restrict__ mLT, const short* __restrict__ mRT,
        float* __restrict__ out, int N)
{
    __shared__ __align__(16) float Xb[2][4096];   // 2 x 16KB x-tile (swizzled)
    __shared__ __align__(16) char  STb[8192];     // S^T bf16 64x64 (swizzled)

    const int lane = threadIdx.x & 63;
    const int m = lane & 15, q = lane >> 4;
    const int s8 = m & 7;                         // XOR swizzle key (row & 7)

    // P-row frags (B-operand of P^T in phase B) and Q^T frags (B-operand in A)
    short8 pf[4][2], qf[4][2];
#pragma unroll
    for (int r = 0; r < 4; ++r) {
        pf[r][0] = *(const short8*)&mLT[(r * 16 + m) * 64 + q * 8];
        pf[r][1] = *(const short8*)&mLT[(r * 16 + m) * 64 + 32 + q * 8];
        qf[r][0] = *(const short8*)&mRT[(r * 16 + m) * 64 + q * 8];
        qf[r][1] = *(const short8*)&mRT[(r * 16 + m) * 64 + 32 + q * 8];
    }

    // dscale pinned in 64 VGPRs (identical for every matrix)
    const int loff = m * 64 + q * 8;
    floatx4 dsr[16];
#pragma unroll
    for (int rt = 0; rt < 4; ++rt) {
        const float* dp = dsc + rt * 1024 + loff;
        dsr[rt * 4 + 0] = *(const floatx4*)&dp[0];
        dsr[rt * 4 + 1] = *(const floatx4*)&dp[4];
        dsr[rt * 4 + 2] = *(const floatx4*)&dp[32];
        dsr[rt * 4 + 3] = *(const floatx4*)&dp[36];
    }

    const long n0 = (long)blockIdx.x * MPW;
    if (n0 >= N) return;
    const int nm = ((long)N - n0 < MPW) ? (int)((long)N - n0) : MPW;

    const char* xg = (const char*)(x + (size_t)n0 * 4096);

    // Per-lane DMA source byte offset inside a 1KB row-block (4 rows x 256B).
    // LDS[row][c] must hold global[row][c ^ (row&7)] so that reading LDS at
    // chunk (c ^ row&7) returns global chunk c.  row = 4j + (lane>>4), so the
    // XOR key depends on j parity only (4j mod 8 = 0 or 4).
    const int rl = lane >> 4;          // row within 4-row block
    const int ck = lane & 15;          // 16B chunk within 256B row
    const int src_even = rl * 256 + ((ck ^ (rl & 7)) << 4);
    const int src_odd  = rl * 256 + ((ck ^ ((4 + rl) & 7)) << 4);

#define DMA_MAT(nidx, buf)  do {                                              \
    const char* gsrc_ = xg + (size_t)(nidx) * 16384;                          \
    char* lb_ = (char*)&Xb[(buf)][0];                                         \
    _Pragma("unroll")                                                         \
    for (int j_ = 0; j_ < 16; ++j_) {                                         \
        __builtin_amdgcn_global_load_lds(                                     \
            (const AS1 void*)(gsrc_ + j_ * 1024 +                             \
                              ((j_ & 1) ? src_odd : src_even)),               \
            (AS3 void*)(lb_ + j_ * 1024), 16, 0, 0);                          \
    }                                                                         \
} while (0)

    // prologue: DMA matrix 0
    DMA_MAT(0, 0);

    for (int i = 0; i < nm; ++i) {
        // pin program order: prior stores stay BEFORE the next DMA issue
        asm volatile("" ::: "memory");
        if (i + 1 < nm) DMA_MAT(i + 1, (i + 1) & 1);

        // Counted wait for DMA(i): allow everything issued after it to stay
        // in flight.  middle iters: stores(i-1)=16 + DMA(i+1)=16 -> vmcnt(32)
        // first/last iter: only 16 newer ops -> vmcnt(16).
        if (nm == 1)                      asm volatile("s_waitcnt vmcnt(0)"  ::: "memory");
        else if (i == 0 || i + 1 == nm)   asm volatile("s_waitcnt vmcnt(16)" ::: "memory");
        else                              asm volatile("s_waitcnt vmcnt(32)" ::: "memory");

        const float* xb = &Xb[i & 1][0];

        // ---- phase A: S = Xs @ Q ; write S^T (swizzled) to LDS
#pragma unroll
        for (int rt = 0; rt < 4; ++rt) {
            const int rbase = (rt * 16 + m) * 64;
            floatx4 x0 = *(const floatx4*)&xb[rbase + (((2 * q)     ^ s8) << 2)];
            floatx4 x1 = *(const floatx4*)&xb[rbase + (((2 * q + 1) ^ s8) << 2)];
            floatx4 x2 = *(const floatx4*)&xb[rbase + (((8 + 2 * q) ^ s8) << 2)];
            floatx4 x3 = *(const floatx4*)&xb[rbase + (((9 + 2 * q) ^ s8) << 2)];
            short8 a0 = pack_bf16(x0 * dsr[rt * 4 + 0], x1 * dsr[rt * 4 + 1]); // k 0..31
            short8 a1 = pack_bf16(x2 * dsr[rt * 4 + 2], x3 * dsr[rt * 4 + 3]); // k 32..63
#pragma unroll
            for (int c = 0; c < 4; ++c) {
                floatx4 s = {0.f, 0.f, 0.f, 0.f};
                s = MFMA(a0, qf[c][0], s);
                s = MFMA(a1, qf[c][1], s);
                short4v pk = { f2bf(s.x), f2bf(s.y), f2bf(s.z), f2bf(s.w) };
                // S^T row = c*16+m, col bytes rt*32+q*8 -> chunk 2rt+(q>>1)
                *(short4v*)&STb[(c * 16 + m) * 128 +
                                (((2 * rt + (q >> 1)) ^ s8) << 4) + (q & 1) * 8] = pk;
            }
        }

        // ---- phase B: O^T = S^T @ P^T (operand-swapped) -> dwordx4 stores
        float* op = out + (size_t)(n0 + i) * 4096;
#pragma unroll
        for (int c2 = 0; c2 < 4; ++c2) {
            const int rowb = (c2 * 16 + m) * 128;
            short8 sb0 = *(const short8*)&STb[rowb + ((q       ^ s8) << 4)];
            short8 sb1 = *(const short8*)&STb[rowb + (((4 + q) ^ s8) << 4)];
#pragma unroll
            for (int r = 0; r < 4; ++r) {
                floatx4 o = {0.f, 0.f, 0.f, 0.f};
                o = MFMA(sb0, pf[r][0], o);
                o = MFMA(sb1, pf[r][1], o);
                // lane holds O[r*16+m][c2*16+q*4 .. +3] -> contiguous 16B
                *(floatx4*)&op[(r * 16 + m) * 64 + c2 * 16 + q * 4] = o;
            }
        }
    }
#undef DMA_MAT
}

extern "C" void kernel_launch(void* const* d_in, const int* in_sizes, int n_in,
                              void* d_out, int out_size, void* d_ws, size_t ws_size,
                              hipStream_t stream) {
    const float* x    = (const float*)d_in[0];
    const float* u_l  = (const float*)d_in[1];
    const float* v_l  = (const float*)d_in[2];
    const float* dg_l = (const float*)d_in[3];
    const float* u_r  = (const float*)d_in[4];
    const float* v_r  = (const float*)d_in[5];
    const float* dg_r = (const float*)d_in[6];
    const float* dsc  = (const float*)d_in[7];
    float* out = (float*)d_out;
    short* ws  = (short*)d_ws;   // [0..4095]=m_left^T bf16, [4096..8191]=m_right^T bf16

    int N = in_sizes[0] / 4096;  // 8192 matrices of 64x64

    hipLaunchKernelGGL(k_prep, dim3(2), dim3(256), 0, stream,
                       u_l, v_l, dg_l, u_r, v_r, dg_r, ws);
    int grid = (N + MPW - 1) / MPW;
    hipLaunchKernelGGL(k_main, dim3(grid), dim3(64), 0, stream,
                       x, dsc, ws, ws + 4096, out, N);
}